// Round 2
// baseline (894.248 us; speedup 1.0000x reference)
//
#include <hip/hip_runtime.h>
#include <math.h>

// Problem constants (B=16, T=64, NN=4096, H=1024)
constexpr int kB = 16;
constexpr int kT = 64;
constexpr int kH = 1024;

typedef short bf16x8 __attribute__((ext_vector_type(8)));   // 8 bf16 = 4 VGPR
typedef float floatx4 __attribute__((ext_vector_type(4)));  // MFMA acc

// ---------------------------------------------------------------------------
// bf16 convert helpers. f2bf_rne: exact round-nearest-even (pack kernel).
// f2bf_fast: round-half-away (2 ops) for in-kernel conversion — bias
// negligible vs bf16's 2^-9 quantization.
// ---------------------------------------------------------------------------
__device__ __forceinline__ unsigned short f2bf_rne(float f) {
    unsigned u = __float_as_uint(f);
    u = u + 0x7FFFu + ((u >> 16) & 1u);
    return (unsigned short)(u >> 16);
}
__device__ __forceinline__ unsigned f2bf_fast_u(float f) {
    return (__float_as_uint(f) + 0x8000u) >> 16;
}
__device__ __forceinline__ uint4 pack8(const float4 a, const float4 b) {
    uint4 r;
    r.x = f2bf_fast_u(a.x) | (f2bf_fast_u(a.y) << 16);
    r.y = f2bf_fast_u(a.z) | (f2bf_fast_u(a.w) << 16);
    r.z = f2bf_fast_u(b.x) | (f2bf_fast_u(b.y) << 16);
    r.w = f2bf_fast_u(b.z) | (f2bf_fast_u(b.w) << 16);
    return r;
}

__global__ __launch_bounds__(256)
void pack_bf16(const float* __restrict__ src, unsigned short* __restrict__ dst,
               int n4)
{
    const int i = blockIdx.x * 256 + threadIdx.x;
    if (i < n4) {
        const float4 v = ((const float4*)src)[i];
        ushort4 o;
        o.x = f2bf_rne(v.x); o.y = f2bf_rne(v.y);
        o.z = f2bf_rne(v.z); o.w = f2bf_rne(v.w);
        ((ushort4*)dst)[i] = o;
    }
}

// ---------------------------------------------------------------------------
// 64x64-tile fp32 GEMM (decoder only; M=16 guard): C = X@W^T + bias
// ---------------------------------------------------------------------------
#define GBM 64
#define GBN 64
#define GBK 16
#define GPAD 4

__global__ __launch_bounds__(256)
void gemm_nt_bias(const float* __restrict__ X, const float* __restrict__ W,
                  const float* __restrict__ bias, float* __restrict__ C,
                  int M, int N, int K)
{
    __shared__ float Xs[GBK][GBM + GPAD];
    __shared__ float Ws[GBK][GBN + GPAD];

    const int tid = threadIdx.x;
    const int bm = blockIdx.y * GBM;
    const int bn = blockIdx.x * GBN;
    const int tm = (tid >> 4) * 4;
    const int tn = (tid & 15) * 4;
    const int lr = tid >> 2;
    const int lc = (tid & 3) * 4;

    float acc[4][4] = {};

    for (int k0 = 0; k0 < K; k0 += GBK) {
        {
            const int gr = bm + lr;
            float4 v = make_float4(0.f, 0.f, 0.f, 0.f);
            if (gr < M) v = *(const float4*)(X + (long)gr * K + k0 + lc);
            Xs[lc + 0][lr] = v.x; Xs[lc + 1][lr] = v.y;
            Xs[lc + 2][lr] = v.z; Xs[lc + 3][lr] = v.w;
        }
        {
            const int gr = bn + lr;
            const float4 v = *(const float4*)(W + (long)gr * K + k0 + lc);
            Ws[lc + 0][lr] = v.x; Ws[lc + 1][lr] = v.y;
            Ws[lc + 2][lr] = v.z; Ws[lc + 3][lr] = v.w;
        }
        __syncthreads();
        #pragma unroll
        for (int k = 0; k < GBK; ++k) {
            const float4 a4 = *(const float4*)&Xs[k][tm];
            const float4 b4 = *(const float4*)&Ws[k][tn];
            acc[0][0] += a4.x * b4.x; acc[0][1] += a4.x * b4.y; acc[0][2] += a4.x * b4.z; acc[0][3] += a4.x * b4.w;
            acc[1][0] += a4.y * b4.x; acc[1][1] += a4.y * b4.y; acc[1][2] += a4.y * b4.z; acc[1][3] += a4.y * b4.w;
            acc[2][0] += a4.z * b4.x; acc[2][1] += a4.z * b4.y; acc[2][2] += a4.z * b4.z; acc[2][3] += a4.z * b4.w;
            acc[3][0] += a4.w * b4.x; acc[3][1] += a4.w * b4.y; acc[3][2] += a4.w * b4.z; acc[3][3] += a4.w * b4.w;
        }
        __syncthreads();
    }

    #pragma unroll
    for (int i = 0; i < 4; ++i) {
        const int gr = bm + tm + i;
        if (gr >= M) continue;
        #pragma unroll
        for (int jj = 0; jj < 4; ++jj) {
            const int gc = bn + tn + jj;
            C[(long)gr * N + gc] = acc[i][jj] + bias[gc];
        }
    }
}

// ---------------------------------------------------------------------------
// Phase-A MFMA GEMM: C[M,N] = X[M,K] @ W[N,K]^T + bias, fp32 in / fp32 out,
// bf16 internally (converted during LDS staging). Unchanged this round —
// next optimization target (143 us @ ~180 TF).
// ---------------------------------------------------------------------------
__global__ __launch_bounds__(256)
void gemm_mfma_a(const float* __restrict__ X,   // [M,K]
                 const float* __restrict__ W,   // [N,K]
                 const float* __restrict__ bias,// [N]
                 float* __restrict__ C,         // [M,N]
                 int M, int N, int K)
{
    __shared__ __attribute__((aligned(16))) unsigned short As[64 * 40];
    __shared__ __attribute__((aligned(16))) unsigned short Bs[128 * 40];

    const int tid  = threadIdx.x;
    const int lane = tid & 63;
    const int w    = tid >> 6;
    const int qm   = w & 1;            // 0..1 (32-row half)
    const int qn   = w >> 1;           // 0..1 (64-col half)
    const int bm   = blockIdx.y * 64;
    const int bn   = blockIdx.x * 128;
    const int al   = lane & 15;
    const int aq   = lane >> 4;

    floatx4 acc[2][4];
    #pragma unroll
    for (int i = 0; i < 2; ++i)
        #pragma unroll
        for (int j = 0; j < 4; ++j)
            acc[i][j] = (floatx4){0.f, 0.f, 0.f, 0.f};

    const int ar = tid >> 2;           // A row 0..63
    const int ak = (tid & 3) * 8;      // A k-offset {0,8,16,24}

    for (int k0 = 0; k0 < K; k0 += 32) {
        const float* ap = X + (long)(bm + ar) * K + k0 + ak;
        const float4 av0 = *(const float4*)(ap);
        const float4 av1 = *(const float4*)(ap + 4);
        float4 bv0[2], bv1[2];
        #pragma unroll
        for (int l = 0; l < 2; ++l) {
            const int c = tid + 256 * l;        // 0..511
            const float* bp = W + (long)(bn + (c >> 2)) * K + k0 + (c & 3) * 8;
            bv0[l] = *(const float4*)(bp);
            bv1[l] = *(const float4*)(bp + 4);
        }
        __syncthreads();   // previous tile's readers done
        *(uint4*)&As[ar * 40 + ak] = pack8(av0, av1);
        #pragma unroll
        for (int l = 0; l < 2; ++l) {
            const int c = tid + 256 * l;
            *(uint4*)&Bs[(c >> 2) * 40 + (c & 3) * 8] = pack8(bv0[l], bv1[l]);
        }
        __syncthreads();

        bf16x8 a[2], b[4];
        #pragma unroll
        for (int i = 0; i < 2; ++i)
            a[i] = *(const bf16x8*)&As[(qm * 32 + i * 16 + al) * 40 + aq * 8];
        #pragma unroll
        for (int j = 0; j < 4; ++j)
            b[j] = *(const bf16x8*)&Bs[(qn * 64 + j * 16 + al) * 40 + aq * 8];
        #pragma unroll
        for (int i = 0; i < 2; ++i)
            #pragma unroll
            for (int j = 0; j < 4; ++j)
                acc[i][j] = __builtin_amdgcn_mfma_f32_16x16x32_bf16(
                    a[i], b[j], acc[i][j], 0, 0, 0);
    }

    #pragma unroll
    for (int i = 0; i < 2; ++i) {
        #pragma unroll
        for (int j = 0; j < 4; ++j) {
            const int row0 = bm + qm * 32 + i * 16 + aq * 4;
            const int col  = bn + qn * 64 + j * 16 + al;
            const float bv = bias[col];
            #pragma unroll
            for (int r = 0; r < 4; ++r)
                C[(long)(row0 + r) * N + col] = acc[i][j][r] + bv;
        }
    }
}

// ---------------------------------------------------------------------------
// PERSISTENT fused pipelined GRU v2. One launch, 65 in-kernel steps.
//
// vs v1 (550 us): the per-step LDS staging phase is deleted.
//  - h lives in GLOBAL as bf16 (quantized with f2bf_fast at WRITE — the
//    identical value the dots consumed before, so numerics are bit-identical).
//  - MFMA A-fragments are read DIRECTLY from the global bf16 h buffers
//    (fragment addressing al*kH + kh*256 + s*32 + aq*8 needs no LDS layout).
//    8 independent 16B loads/wave issue right after the grid barrier.
//  - hp (the z*h recursion input) is a per-thread fp32 REGISTER carry:
//    thread (b,j) computed exactly that value one step earlier. fp32 h is
//    written to global only at the last step (decoder input).
//  - part exchange: floatx4 part[12][3][64] -> ds_write_b128 contiguous
//    (conflict-free) instead of the 4-way-conflicting scalar layout.
//
// Grid barrier unchanged (proved correct in v1): 64 blocks, 1 block/CU,
// all co-resident; release atomicAdd + relaxed spin + __threadfence().
// ---------------------------------------------------------------------------
__global__ __launch_bounds__(768, 3)
void fused_gru_persistent(const float* __restrict__ gx0,
                          const unsigned short* __restrict__ w0, const float* __restrict__ bb0,
                          const unsigned short* __restrict__ w1, const float* __restrict__ bb1,
                          const unsigned short* __restrict__ w2, const float* __restrict__ bb2,
                          unsigned short* __restrict__ h1bf0, unsigned short* __restrict__ h1bf1,
                          unsigned short* __restrict__ h2bf0, unsigned short* __restrict__ h2bf1,
                          float* __restrict__ h2last, unsigned* __restrict__ bar)
{
    __shared__ __attribute__((aligned(16))) floatx4 part[12][3][64]; // [wid][g][lane]

    const int tid   = threadIdx.x;     // 0..767
    const int lane  = tid & 63;
    const int wid   = tid >> 6;        // 0..11
    const int jbase = blockIdx.x * 16;

    const int m  = wid >> 2;           // matrix: 0 w_hh0, 1 w_ih1, 2 w_hh1
    const int kh = wid & 3;            // K-quarter
    const int al = lane & 15;
    const int aq = lane >> 4;

    // ---- one-time: weight fragments -> registers (96 VGPR/lane) ----
    const unsigned short* Wm = (m == 0) ? w0 : (m == 1) ? w1 : w2;
    const long wbase = (long)(jbase + al) * kH + kh * 256 + aq * 8;
    bf16x8 wreg[3][8];
    #pragma unroll
    for (int g = 0; g < 3; ++g)
        #pragma unroll
        for (int s = 0; s < 8; ++s)
            wreg[g][s] = *(const bf16x8*)(Wm + (long)g * kH * kH + wbase + s * 32);

    // ---- one-time: update-phase bias preload (tid<256 only) ----
    const int ub  = tid >> 4;          // batch row for update phase
    const int ujj = tid & 15;
    const int ujg = jbase + ujj;
    const float b0r = bb0[ujg], b0z = bb0[kH + ujg], b0n = bb0[2 * kH + ujg];
    const float b1r = bb1[ujg], b1z = bb1[kH + ujg], b1n = bb1[2 * kH + ujg];
    const float b2r = bb2[ujg], b2z = bb2[kH + ujg], b2n = bb2[2 * kH + ujg];

    // per-thread fp32 recursion state (update threads only)
    float h1reg = 0.f;   // h1_{k-1} for this (b,j)
    float h2reg = 0.f;   // h2_{k-2} for this (b,j)

    // A-fragment offset within an h buffer (elements)
    const int aoff = al * kH + kh * 256 + aq * 8;
    const int pl   = (ub >> 2) * 16 + ujj;   // part lane index for update read
    const int pr   = ub & 3;                 // part reg index

    for (int k = 0; k <= kT; ++k) {
        // ping-pong pointers (same mapping as before)
        const unsigned short* h1p = (k & 1) ? h1bf0 : h1bf1;   // h1_{k-1}
        unsigned short*       h1o = (k & 1) ? h1bf1 : h1bf0;   // h1_k
        const unsigned short* h2p = (k & 1) ? h2bf1 : h2bf0;   // h2_{k-2}
        unsigned short*       h2o = (k & 1) ? h2bf0 : h2bf1;   // h2_{k-1}

        // ---- issue gx0 loads early (read-only data; hides under MFMA) ----
        float xr0 = 0.f, xz0 = 0.f, xn0 = 0.f;
        if (tid < 256 && k < kT) {
            const float* gxrow = gx0 + (long)ub * (kT * 3 * kH) + (long)k * 3 * kH;
            xr0 = gxrow[ujg];
            xz0 = gxrow[kH + ujg];
            xn0 = gxrow[2 * kH + ujg];
        }

        // ---- A-fragments direct from global bf16 h ----
        const bool azero = (m < 2) ? (k == 0) : (k <= 1);
        const unsigned short* hsrc = (m < 2) ? h1p : h2p;
        bf16x8 a[8];
        #pragma unroll
        for (int s = 0; s < 8; ++s) {
            if (azero) a[s] = (bf16x8){0, 0, 0, 0, 0, 0, 0, 0};
            else       a[s] = *(const bf16x8*)(hsrc + aoff + s * 32);
        }

        // ---- 24 MFMAs (weights + A in registers) ----
        floatx4 acc[3];
        #pragma unroll
        for (int g = 0; g < 3; ++g) acc[g] = (floatx4){0.f, 0.f, 0.f, 0.f};
        #pragma unroll
        for (int s = 0; s < 8; ++s)
            #pragma unroll
            for (int g = 0; g < 3; ++g)
                acc[g] = __builtin_amdgcn_mfma_f32_16x16x32_bf16(
                    a[s], wreg[g][s], acc[g], 0, 0, 0);

        #pragma unroll
        for (int g = 0; g < 3; ++g)
            part[wid][g][lane] = acc[g];     // ds_write_b128, conflict-free
        __syncthreads();

        // ---- cell updates (256 threads: b = tid>>4, j = tid&15) ----
        if (tid < 256) {
            // gh[m][g] = sum over kh of D[b][j] partials
            float gh[3][3];
            #pragma unroll
            for (int mm = 0; mm < 3; ++mm)
                #pragma unroll
                for (int g = 0; g < 3; ++g)
                    gh[mm][g] = part[mm * 4 + 0][g][pl][pr] + part[mm * 4 + 1][g][pl][pr]
                              + part[mm * 4 + 2][g][pl][pr] + part[mm * 4 + 3][g][pl][pr];

            if (k < kT) {   // layer0 step t=k
                const float hr = gh[0][0] + b0r;
                const float hz = gh[0][1] + b0z;
                const float hn = gh[0][2] + b0n;
                const float r = 1.f / (1.f + __expf(-(xr0 + hr)));
                const float z = 1.f / (1.f + __expf(-(xz0 + hz)));
                const float n = tanhf(xn0 + r * hn);
                const float hnew = (1.f - z) * n + z * h1reg;
                h1reg = hnew;
                h1o[ub * kH + ujg] = (unsigned short)f2bf_fast_u(hnew);
            }
            if (k > 0) {    // layer1 step t=k-1; gx1 = gh[1] + b_ih1
                const float xr = gh[1][0] + b1r;
                const float xz = gh[1][1] + b1z;
                const float xn = gh[1][2] + b1n;
                const float hr = gh[2][0] + b2r;
                const float hz = gh[2][1] + b2z;
                const float hn = gh[2][2] + b2n;
                const float r = 1.f / (1.f + __expf(-(xr + hr)));
                const float z = 1.f / (1.f + __expf(-(xz + hz)));
                const float n = tanhf(xn + r * hn);
                const float hnew = (1.f - z) * n + z * h2reg;
                h2reg = hnew;
                h2o[ub * kH + ujg] = (unsigned short)f2bf_fast_u(hnew);
                if (k == kT) h2last[(long)ub * kH + ujg] = hnew;  // fp32 for decoder
            }
        }

        // ---- device-scope grid barrier (skip after last step) ----
        if (k < kT) {
            __syncthreads();          // all block writes complete
            if (tid == 0) {
                __hip_atomic_fetch_add(bar, 1u, __ATOMIC_RELEASE,
                                       __HIP_MEMORY_SCOPE_AGENT);
                const unsigned target = (unsigned)(k + 1) * 64u;
                while (__hip_atomic_load(bar, __ATOMIC_RELAXED,
                                         __HIP_MEMORY_SCOPE_AGENT) < target)
                    __builtin_amdgcn_s_sleep(2);
                __threadfence();      // acquire: invalidate stale L1/L2 lines
            }
            __syncthreads();
        }
    }
}

// ---------------------------------------------------------------------------
// kernel_launch
// ---------------------------------------------------------------------------
extern "C" void kernel_launch(void* const* d_in, const int* in_sizes, int n_in,
                              void* d_out, int out_size, void* d_ws, size_t ws_size,
                              hipStream_t stream)
{
    const float* x        = (const float*)d_in[0];   // [16,64,4096]
    const float* w_ih_l0  = (const float*)d_in[1];   // [3072,4096]
    const float* w_hh_l0  = (const float*)d_in[2];   // [3072,1024]
    const float* b_ih_l0  = (const float*)d_in[3];   // [3072]
    const float* b_hh_l0  = (const float*)d_in[4];   // [3072]
    const float* w_ih_l1  = (const float*)d_in[5];   // [3072,1024]
    const float* w_hh_l1  = (const float*)d_in[6];   // [3072,1024]
    const float* b_ih_l1  = (const float*)d_in[7];   // [3072]
    const float* b_hh_l1  = (const float*)d_in[8];   // [3072]
    const float* dec_w    = (const float*)d_in[9];   // [4096,1024]
    const float* dec_b    = (const float*)d_in[10];  // [4096]
    float* out = (float*)d_out;                      // [16,4096]

    // Workspace: gx0 12 MB + 4 bf16 h-bufs 128 KB + h2last 64 KB +
    // 3 bf16 matrices 18 MB + barrier counter.
    float* ws    = (float*)d_ws;
    float* gx0   = ws;                                  // [1024,3072] rows b*T+t
    unsigned short* h1bf0 = (unsigned short*)(gx0 + (size_t)1024 * 3072);
    unsigned short* h1bf1 = h1bf0 + (size_t)kB * kH;
    unsigned short* h2bf0 = h1bf1 + (size_t)kB * kH;
    unsigned short* h2bf1 = h2bf0 + (size_t)kB * kH;
    float* h2last = (float*)(h2bf1 + (size_t)kB * kH);
    unsigned short* wbf0 = (unsigned short*)(h2last + (size_t)kB * kH);
    unsigned short* wbf1 = wbf0 + (size_t)3 * kH * kH;
    unsigned short* wbf2 = wbf1 + (size_t)3 * kH * kH;
    unsigned* bar = (unsigned*)(wbf2 + (size_t)3 * kH * kH);

    // Barrier counter must start at 0 each replay (memset node in the graph).
    hipMemsetAsync(bar, 0, 128, stream);

    const int wn4 = 3 * kH * kH / 4;

    // Pack recurrence weights fp32 -> bf16 (RNE)
    pack_bf16<<<(wn4 + 255) / 256, 256, 0, stream>>>(w_hh_l0, wbf0, wn4);
    pack_bf16<<<(wn4 + 255) / 256, 256, 0, stream>>>(w_ih_l1, wbf1, wn4);
    pack_bf16<<<(wn4 + 255) / 256, 256, 0, stream>>>(w_hh_l1, wbf2, wn4);

    // Phase A (MFMA bf16): gx0 = x @ w_ih_l0^T + b_ih_l0  (M=1024,N=3072,K=4096)
    gemm_mfma_a<<<dim3(3072 / 128, 1024 / 64), 256, 0, stream>>>(
        x, w_ih_l0, b_ih_l0, gx0, 1024, 3072, 4096);

    // Persistent fused recurrence: ONE launch, 65 in-kernel steps.
    fused_gru_persistent<<<64, 768, 0, stream>>>(
        gx0, wbf0, b_hh_l0, wbf1, b_ih_l1, wbf2, b_hh_l1,
        h1bf0, h1bf1, h2bf0, h2bf1, h2last, bar);

    // Decoder (fp32): out = h2_last @ dec_w^T + dec_b  (M=16,N=4096,K=1024)
    gemm_nt_bias<<<dim3(4096 / GBN, 1), 256, 0, stream>>>(
        h2last, dec_w, dec_b, out, kB, 4096, 1024);
}

// Round 4
// 786.745 us; speedup vs baseline: 1.1366x; 1.1366x over previous
//
#include <hip/hip_runtime.h>
#include <math.h>

// Problem constants (B=16, T=64, NN=4096, H=1024)
constexpr int kB = 16;
constexpr int kT = 64;
constexpr int kH = 1024;

typedef short bf16x8 __attribute__((ext_vector_type(8)));   // 8 bf16 = 4 VGPR
typedef float floatx4 __attribute__((ext_vector_type(4)));  // MFMA acc

// ---------------------------------------------------------------------------
// bf16 convert helpers. f2bf_rne: exact round-nearest-even (pack kernel).
// f2bf_fast: round-half-away (2 ops) for in-kernel conversion — bias
// negligible vs bf16's 2^-9 quantization.
// ---------------------------------------------------------------------------
__device__ __forceinline__ unsigned short f2bf_rne(float f) {
    unsigned u = __float_as_uint(f);
    u = u + 0x7FFFu + ((u >> 16) & 1u);
    return (unsigned short)(u >> 16);
}
__device__ __forceinline__ unsigned f2bf_fast_u(float f) {
    return (__float_as_uint(f) + 0x8000u) >> 16;
}
__device__ __forceinline__ uint4 pack8(const float4 a, const float4 b) {
    uint4 r;
    r.x = f2bf_fast_u(a.x) | (f2bf_fast_u(a.y) << 16);
    r.y = f2bf_fast_u(a.z) | (f2bf_fast_u(a.w) << 16);
    r.z = f2bf_fast_u(b.x) | (f2bf_fast_u(b.y) << 16);
    r.w = f2bf_fast_u(b.z) | (f2bf_fast_u(b.w) << 16);
    return r;
}

__global__ __launch_bounds__(256)
void pack_bf16(const float* __restrict__ src, unsigned short* __restrict__ dst,
               int n4)
{
    const int i = blockIdx.x * 256 + threadIdx.x;
    if (i < n4) {
        const float4 v = ((const float4*)src)[i];
        ushort4 o;
        o.x = f2bf_rne(v.x); o.y = f2bf_rne(v.y);
        o.z = f2bf_rne(v.z); o.w = f2bf_rne(v.w);
        ((ushort4*)dst)[i] = o;
    }
}

// ---------------------------------------------------------------------------
// 64x64-tile fp32 GEMM (decoder only; M=16 guard): C = X@W^T + bias
// ---------------------------------------------------------------------------
#define GBM 64
#define GBN 64
#define GBK 16
#define GPAD 4

__global__ __launch_bounds__(256)
void gemm_nt_bias(const float* __restrict__ X, const float* __restrict__ W,
                  const float* __restrict__ bias, float* __restrict__ C,
                  int M, int N, int K)
{
    __shared__ float Xs[GBK][GBM + GPAD];
    __shared__ float Ws[GBK][GBN + GPAD];

    const int tid = threadIdx.x;
    const int bm = blockIdx.y * GBM;
    const int bn = blockIdx.x * GBN;
    const int tm = (tid >> 4) * 4;
    const int tn = (tid & 15) * 4;
    const int lr = tid >> 2;
    const int lc = (tid & 3) * 4;

    float acc[4][4] = {};

    for (int k0 = 0; k0 < K; k0 += GBK) {
        {
            const int gr = bm + lr;
            float4 v = make_float4(0.f, 0.f, 0.f, 0.f);
            if (gr < M) v = *(const float4*)(X + (long)gr * K + k0 + lc);
            Xs[lc + 0][lr] = v.x; Xs[lc + 1][lr] = v.y;
            Xs[lc + 2][lr] = v.z; Xs[lc + 3][lr] = v.w;
        }
        {
            const int gr = bn + lr;
            const float4 v = *(const float4*)(W + (long)gr * K + k0 + lc);
            Ws[lc + 0][lr] = v.x; Ws[lc + 1][lr] = v.y;
            Ws[lc + 2][lr] = v.z; Ws[lc + 3][lr] = v.w;
        }
        __syncthreads();
        #pragma unroll
        for (int k = 0; k < GBK; ++k) {
            const float4 a4 = *(const float4*)&Xs[k][tm];
            const float4 b4 = *(const float4*)&Ws[k][tn];
            acc[0][0] += a4.x * b4.x; acc[0][1] += a4.x * b4.y; acc[0][2] += a4.x * b4.z; acc[0][3] += a4.x * b4.w;
            acc[1][0] += a4.y * b4.x; acc[1][1] += a4.y * b4.y; acc[1][2] += a4.y * b4.z; acc[1][3] += a4.y * b4.w;
            acc[2][0] += a4.z * b4.x; acc[2][1] += a4.z * b4.y; acc[2][2] += a4.z * b4.z; acc[2][3] += a4.z * b4.w;
            acc[3][0] += a4.w * b4.x; acc[3][1] += a4.w * b4.y; acc[3][2] += a4.w * b4.z; acc[3][3] += a4.w * b4.w;
        }
        __syncthreads();
    }

    #pragma unroll
    for (int i = 0; i < 4; ++i) {
        const int gr = bm + tm + i;
        if (gr >= M) continue;
        #pragma unroll
        for (int jj = 0; jj < 4; ++jj) {
            const int gc = bn + tn + jj;
            C[(long)gr * N + gc] = acc[i][jj] + bias[gc];
        }
    }
}

// ---------------------------------------------------------------------------
// Phase-A MFMA GEMM: C[M,N] = X[M,K] @ W[N,K]^T + bias, fp32 in / fp32 out,
// bf16 internally (converted during LDS staging). Unchanged.
// ---------------------------------------------------------------------------
__global__ __launch_bounds__(256)
void gemm_mfma_a(const float* __restrict__ X,   // [M,K]
                 const float* __restrict__ W,   // [N,K]
                 const float* __restrict__ bias,// [N]
                 float* __restrict__ C,         // [M,N]
                 int M, int N, int K)
{
    __shared__ __attribute__((aligned(16))) unsigned short As[64 * 40];
    __shared__ __attribute__((aligned(16))) unsigned short Bs[128 * 40];

    const int tid  = threadIdx.x;
    const int lane = tid & 63;
    const int w    = tid >> 6;
    const int qm   = w & 1;            // 0..1 (32-row half)
    const int qn   = w >> 1;           // 0..1 (64-col half)
    const int bm   = blockIdx.y * 64;
    const int bn   = blockIdx.x * 128;
    const int al   = lane & 15;
    const int aq   = lane >> 4;

    floatx4 acc[2][4];
    #pragma unroll
    for (int i = 0; i < 2; ++i)
        #pragma unroll
        for (int j = 0; j < 4; ++j)
            acc[i][j] = (floatx4){0.f, 0.f, 0.f, 0.f};

    const int ar = tid >> 2;           // A row 0..63
    const int ak = (tid & 3) * 8;      // A k-offset {0,8,16,24}

    for (int k0 = 0; k0 < K; k0 += 32) {
        const float* ap = X + (long)(bm + ar) * K + k0 + ak;
        const float4 av0 = *(const float4*)(ap);
        const float4 av1 = *(const float4*)(ap + 4);
        float4 bv0[2], bv1[2];
        #pragma unroll
        for (int l = 0; l < 2; ++l) {
            const int c = tid + 256 * l;        // 0..511
            const float* bp = W + (long)(bn + (c >> 2)) * K + k0 + (c & 3) * 8;
            bv0[l] = *(const float4*)(bp);
            bv1[l] = *(const float4*)(bp + 4);
        }
        __syncthreads();   // previous tile's readers done
        *(uint4*)&As[ar * 40 + ak] = pack8(av0, av1);
        #pragma unroll
        for (int l = 0; l < 2; ++l) {
            const int c = tid + 256 * l;
            *(uint4*)&Bs[(c >> 2) * 40 + (c & 3) * 8] = pack8(bv0[l], bv1[l]);
        }
        __syncthreads();

        bf16x8 a[2], b[4];
        #pragma unroll
        for (int i = 0; i < 2; ++i)
            a[i] = *(const bf16x8*)&As[(qm * 32 + i * 16 + al) * 40 + aq * 8];
        #pragma unroll
        for (int j = 0; j < 4; ++j)
            b[j] = *(const bf16x8*)&Bs[(qn * 64 + j * 16 + al) * 40 + aq * 8];
        #pragma unroll
        for (int i = 0; i < 2; ++i)
            #pragma unroll
            for (int j = 0; j < 4; ++j)
                acc[i][j] = __builtin_amdgcn_mfma_f32_16x16x32_bf16(
                    a[i], b[j], acc[i][j], 0, 0, 0);
    }

    #pragma unroll
    for (int i = 0; i < 2; ++i) {
        #pragma unroll
        for (int j = 0; j < 4; ++j) {
            const int row0 = bm + qm * 32 + i * 16 + aq * 4;
            const int col  = bn + qn * 64 + j * 16 + al;
            const float bv = bias[col];
            #pragma unroll
            for (int r = 0; r < 4; ++r)
                C[(long)(row0 + r) * N + col] = acc[i][j][r] + bv;
        }
    }
}

// ---------------------------------------------------------------------------
// PERSISTENT fused pipelined GRU v3b. One launch, 65 in-kernel steps.
//
// vs v2 (575 us): centralized atomic barrier replaced (v2 counters showed
// sync-latency-bound: FETCH/VALU dropped, time didn't — the 64 serialized
// same-line RMWs + hot-line spin ARE the step). New barrier:
//  - flags[64], 16B apart: each block RELEASE-stores its own slot (parallel
//    arrivals, zero RMW contention).
//  - every block's wave 0 polls ALL flags, one per lane (lane i watches
//    block i); wave exits when all lanes satisfied. No block0 "go" hop.
//  - single ACQUIRE fence (agent scope) after the poll — same
//    release->flag->acquire visibility chain as the proven v1/v2 barrier.
//    Monotonic gens (>= test) make late pollers safe.
// Also: next-step gx0 prefetched into registers BEFORE the barrier
// (read-only, fence-independent) so HBM latency hides under the wait.
// v3b fix: __hip_atomic_fence doesn't exist in this ROCm; use
// __builtin_amdgcn_fence(__ATOMIC_ACQUIRE, "agent").
// ---------------------------------------------------------------------------
#define FLAG_STRIDE 4   // uints; 16 B between flags

__global__ __launch_bounds__(768, 3)
void fused_gru_persistent(const float* __restrict__ gx0,
                          const unsigned short* __restrict__ w0, const float* __restrict__ bb0,
                          const unsigned short* __restrict__ w1, const float* __restrict__ bb1,
                          const unsigned short* __restrict__ w2, const float* __restrict__ bb2,
                          unsigned short* __restrict__ h1bf0, unsigned short* __restrict__ h1bf1,
                          unsigned short* __restrict__ h2bf0, unsigned short* __restrict__ h2bf1,
                          float* __restrict__ h2last, unsigned* __restrict__ flags)
{
    __shared__ __attribute__((aligned(16))) floatx4 part[12][3][64]; // [wid][g][lane]

    const int tid   = threadIdx.x;     // 0..767
    const int lane  = tid & 63;
    const int wid   = tid >> 6;        // 0..11
    const int bx    = blockIdx.x;
    const int jbase = bx * 16;

    const int m  = wid >> 2;           // matrix: 0 w_hh0, 1 w_ih1, 2 w_hh1
    const int kh = wid & 3;            // K-quarter
    const int al = lane & 15;
    const int aq = lane >> 4;

    // ---- one-time: weight fragments -> registers (96 regs/lane) ----
    const unsigned short* Wm = (m == 0) ? w0 : (m == 1) ? w1 : w2;
    const long wbase = (long)(jbase + al) * kH + kh * 256 + aq * 8;
    bf16x8 wreg[3][8];
    #pragma unroll
    for (int g = 0; g < 3; ++g)
        #pragma unroll
        for (int s = 0; s < 8; ++s)
            wreg[g][s] = *(const bf16x8*)(Wm + (long)g * kH * kH + wbase + s * 32);

    // ---- one-time: update-phase bias preload (tid<256 only) ----
    const int ub  = tid >> 4;          // batch row for update phase
    const int ujj = tid & 15;
    const int ujg = jbase + ujj;
    const float b0r = bb0[ujg], b0z = bb0[kH + ujg], b0n = bb0[2 * kH + ujg];
    const float b1r = bb1[ujg], b1z = bb1[kH + ujg], b1n = bb1[2 * kH + ujg];
    const float b2r = bb2[ujg], b2z = bb2[kH + ujg], b2n = bb2[2 * kH + ujg];

    // per-thread fp32 recursion state (update threads only)
    float h1reg = 0.f;   // h1_{k-1} for this (b,j)
    float h2reg = 0.f;   // h2_{k-2} for this (b,j)

    // A-fragment offset within an h buffer (elements)
    const int aoff = al * kH + kh * 256 + aq * 8;
    const int pl   = (ub >> 2) * 16 + ujj;   // part lane index for update read
    const int pr   = ub & 3;                 // part reg index

    // gx0 for step 0 preloaded (subsequent steps prefetched under barrier)
    float gxr = 0.f, gxz = 0.f, gxn = 0.f;
    if (tid < 256) {
        const float* g = gx0 + (long)ub * (kT * 3 * kH);
        gxr = g[ujg]; gxz = g[kH + ujg]; gxn = g[2 * kH + ujg];
    }

    for (int k = 0; k <= kT; ++k) {
        // ping-pong pointers
        const unsigned short* h1p = (k & 1) ? h1bf0 : h1bf1;   // h1_{k-1}
        unsigned short*       h1o = (k & 1) ? h1bf1 : h1bf0;   // h1_k
        const unsigned short* h2p = (k & 1) ? h2bf1 : h2bf0;   // h2_{k-2}
        unsigned short*       h2o = (k & 1) ? h2bf0 : h2bf1;   // h2_{k-1}

        // ---- A-fragments direct from global bf16 h ----
        const bool azero = (m < 2) ? (k == 0) : (k <= 1);
        const unsigned short* hsrc = (m < 2) ? h1p : h2p;
        bf16x8 a[8];
        #pragma unroll
        for (int s = 0; s < 8; ++s) {
            if (azero) a[s] = (bf16x8){0, 0, 0, 0, 0, 0, 0, 0};
            else       a[s] = *(const bf16x8*)(hsrc + aoff + s * 32);
        }

        // ---- 24 MFMAs (weights + A in registers) ----
        floatx4 acc[3];
        #pragma unroll
        for (int g = 0; g < 3; ++g) acc[g] = (floatx4){0.f, 0.f, 0.f, 0.f};
        #pragma unroll
        for (int s = 0; s < 8; ++s)
            #pragma unroll
            for (int g = 0; g < 3; ++g)
                acc[g] = __builtin_amdgcn_mfma_f32_16x16x32_bf16(
                    a[s], wreg[g][s], acc[g], 0, 0, 0);

        #pragma unroll
        for (int g = 0; g < 3; ++g)
            part[wid][g][lane] = acc[g];     // ds_write_b128, conflict-free
        __syncthreads();

        // ---- cell updates (256 threads: b = tid>>4, j = tid&15) ----
        if (tid < 256) {
            float gh[3][3];
            #pragma unroll
            for (int mm = 0; mm < 3; ++mm)
                #pragma unroll
                for (int g = 0; g < 3; ++g)
                    gh[mm][g] = part[mm * 4 + 0][g][pl][pr] + part[mm * 4 + 1][g][pl][pr]
                              + part[mm * 4 + 2][g][pl][pr] + part[mm * 4 + 3][g][pl][pr];

            if (k < kT) {   // layer0 step t=k
                const float hr = gh[0][0] + b0r;
                const float hz = gh[0][1] + b0z;
                const float hn = gh[0][2] + b0n;
                const float r = 1.f / (1.f + __expf(-(gxr + hr)));
                const float z = 1.f / (1.f + __expf(-(gxz + hz)));
                const float n = tanhf(gxn + r * hn);
                const float hnew = (1.f - z) * n + z * h1reg;
                h1reg = hnew;
                h1o[ub * kH + ujg] = (unsigned short)f2bf_fast_u(hnew);
            }
            if (k > 0) {    // layer1 step t=k-1; gx1 = gh[1] + b_ih1
                const float xr = gh[1][0] + b1r;
                const float xz = gh[1][1] + b1z;
                const float xn = gh[1][2] + b1n;
                const float hr = gh[2][0] + b2r;
                const float hz = gh[2][1] + b2z;
                const float hn = gh[2][2] + b2n;
                const float r = 1.f / (1.f + __expf(-(xr + hr)));
                const float z = 1.f / (1.f + __expf(-(xz + hz)));
                const float n = tanhf(xn + r * hn);
                const float hnew = (1.f - z) * n + z * h2reg;
                h2reg = hnew;
                h2o[ub * kH + ujg] = (unsigned short)f2bf_fast_u(hnew);
                if (k == kT) h2last[(long)ub * kH + ujg] = hnew;  // fp32 for decoder
            }
        }

        // ---- prefetch gx0 for step k+1 (read-only; hides under barrier) ----
        float nxr = 0.f, nxz = 0.f, nxn = 0.f;
        if (tid < 256 && (k + 1) < kT) {
            const float* g = gx0 + (long)ub * (kT * 3 * kH) + (long)(k + 1) * 3 * kH;
            nxr = g[ujg]; nxz = g[kH + ujg]; nxn = g[2 * kH + ujg];
        }

        // ---- distributed-flag all-poll grid barrier ----
        if (k < kT) {
            __syncthreads();          // block writes drained
            if (wid == 0) {
                const unsigned gen = (unsigned)(k + 1);
                if (lane == 0)
                    __hip_atomic_store(&flags[bx * FLAG_STRIDE], gen,
                                       __ATOMIC_RELEASE, __HIP_MEMORY_SCOPE_AGENT);
                // lane i watches block i's flag; wave exits when all satisfied
                while (__hip_atomic_load(&flags[lane * FLAG_STRIDE],
                                         __ATOMIC_RELAXED,
                                         __HIP_MEMORY_SCOPE_AGENT) < gen) {
                    __builtin_amdgcn_s_sleep(1);
                }
                __builtin_amdgcn_fence(__ATOMIC_ACQUIRE, "agent");
            }
            __syncthreads();
        }

        gxr = nxr; gxz = nxz; gxn = nxn;
    }
}

// ---------------------------------------------------------------------------
// kernel_launch
// ---------------------------------------------------------------------------
extern "C" void kernel_launch(void* const* d_in, const int* in_sizes, int n_in,
                              void* d_out, int out_size, void* d_ws, size_t ws_size,
                              hipStream_t stream)
{
    const float* x        = (const float*)d_in[0];   // [16,64,4096]
    const float* w_ih_l0  = (const float*)d_in[1];   // [3072,4096]
    const float* w_hh_l0  = (const float*)d_in[2];   // [3072,1024]
    const float* b_ih_l0  = (const float*)d_in[3];   // [3072]
    const float* b_hh_l0  = (const float*)d_in[4];   // [3072]
    const float* w_ih_l1  = (const float*)d_in[5];   // [3072,1024]
    const float* w_hh_l1  = (const float*)d_in[6];   // [3072,1024]
    const float* b_ih_l1  = (const float*)d_in[7];   // [3072]
    const float* b_hh_l1  = (const float*)d_in[8];   // [3072]
    const float* dec_w    = (const float*)d_in[9];   // [4096,1024]
    const float* dec_b    = (const float*)d_in[10];  // [4096]
    float* out = (float*)d_out;                      // [16,4096]

    // Workspace: gx0 12 MB + 4 bf16 h-bufs 128 KB + h2last 64 KB +
    // 3 bf16 matrices 18 MB + 1 KB flag array.
    float* ws    = (float*)d_ws;
    float* gx0   = ws;                                  // [1024,3072] rows b*T+t
    unsigned short* h1bf0 = (unsigned short*)(gx0 + (size_t)1024 * 3072);
    unsigned short* h1bf1 = h1bf0 + (size_t)kB * kH;
    unsigned short* h2bf0 = h1bf1 + (size_t)kB * kH;
    unsigned short* h2bf1 = h2bf0 + (size_t)kB * kH;
    float* h2last = (float*)(h2bf1 + (size_t)kB * kH);
    unsigned short* wbf0 = (unsigned short*)(h2last + (size_t)kB * kH);
    unsigned short* wbf1 = wbf0 + (size_t)3 * kH * kH;
    unsigned short* wbf2 = wbf1 + (size_t)3 * kH * kH;
    unsigned* flags = (unsigned*)(wbf2 + (size_t)3 * kH * kH);

    // Flags must start at 0 each replay (memset node in the graph).
    (void)hipMemsetAsync(flags, 0, 64 * FLAG_STRIDE * sizeof(unsigned), stream);

    const int wn4 = 3 * kH * kH / 4;

    // Pack recurrence weights fp32 -> bf16 (RNE)
    pack_bf16<<<(wn4 + 255) / 256, 256, 0, stream>>>(w_hh_l0, wbf0, wn4);
    pack_bf16<<<(wn4 + 255) / 256, 256, 0, stream>>>(w_ih_l1, wbf1, wn4);
    pack_bf16<<<(wn4 + 255) / 256, 256, 0, stream>>>(w_hh_l1, wbf2, wn4);

    // Phase A (MFMA bf16): gx0 = x @ w_ih_l0^T + b_ih_l0  (M=1024,N=3072,K=4096)
    gemm_mfma_a<<<dim3(3072 / 128, 1024 / 64), 256, 0, stream>>>(
        x, w_ih_l0, b_ih_l0, gx0, 1024, 3072, 4096);

    // Persistent fused recurrence: ONE launch, 65 in-kernel steps.
    fused_gru_persistent<<<64, 768, 0, stream>>>(
        gx0, wbf0, b_hh_l0, wbf1, b_ih_l1, wbf2, b_hh_l1,
        h1bf0, h1bf1, h2bf0, h2bf1, h2last, flags);

    // Decoder (fp32): out = h2_last @ dec_w^T + dec_b  (M=16,N=4096,K=1024)
    gemm_nt_bias<<<dim3(4096 / GBN, 1), 256, 0, stream>>>(
        h2last, dec_w, dec_b, out, kB, 4096, 1024);
}

// Round 5
// 691.928 us; speedup vs baseline: 1.2924x; 1.1370x over previous
//
#include <hip/hip_runtime.h>
#include <math.h>

// Problem constants (B=16, T=64, NN=4096, H=1024)
constexpr int kB = 16;
constexpr int kT = 64;
constexpr int kH = 1024;

typedef short bf16x8 __attribute__((ext_vector_type(8)));   // 8 bf16 = 4 VGPR
typedef float floatx4 __attribute__((ext_vector_type(4)));  // MFMA acc

// ---------------------------------------------------------------------------
// bf16 convert helpers. f2bf_rne: exact round-nearest-even (pack kernel).
// f2bf_fast: round-half-away (2 ops) for in-kernel conversion — bias
// negligible vs bf16's 2^-9 quantization.
// ---------------------------------------------------------------------------
__device__ __forceinline__ unsigned short f2bf_rne(float f) {
    unsigned u = __float_as_uint(f);
    u = u + 0x7FFFu + ((u >> 16) & 1u);
    return (unsigned short)(u >> 16);
}
__device__ __forceinline__ unsigned f2bf_fast_u(float f) {
    return (__float_as_uint(f) + 0x8000u) >> 16;
}
__device__ __forceinline__ uint4 pack8(const float4 a, const float4 b) {
    uint4 r;
    r.x = f2bf_fast_u(a.x) | (f2bf_fast_u(a.y) << 16);
    r.y = f2bf_fast_u(a.z) | (f2bf_fast_u(a.w) << 16);
    r.z = f2bf_fast_u(b.x) | (f2bf_fast_u(b.y) << 16);
    r.w = f2bf_fast_u(b.z) | (f2bf_fast_u(b.w) << 16);
    return r;
}

// ---------------------------------------------------------------------------
// Coherence-point (system-scope) memory ops: sc0 sc1 bypass L1 and the
// per-XCD L2, so cross-XCD visibility needs NO release/acquire cache
// maintenance (the wb/inv walks that dominated v3's barrier).
// ---------------------------------------------------------------------------
__device__ __forceinline__ void store_short_sys(unsigned short* p, unsigned v) {
    asm volatile("global_store_short %0, %1, off sc0 sc1"
                 :: "v"(p), "v"(v) : "memory");
}
__device__ __forceinline__ void store_dword_sys(unsigned* p, unsigned v) {
    asm volatile("global_store_dword %0, %1, off sc0 sc1"
                 :: "v"(p), "v"(v) : "memory");
}
__device__ __forceinline__ unsigned load_dword_sys(const unsigned* p) {
    unsigned v;
    asm volatile("global_load_dword %0, %1, off sc0 sc1\n\t"
                 "s_waitcnt vmcnt(0)"
                 : "=v"(v) : "v"(p) : "memory");
    return v;
}

__global__ __launch_bounds__(256)
void pack_bf16(const float* __restrict__ src, unsigned short* __restrict__ dst,
               int n4)
{
    const int i = blockIdx.x * 256 + threadIdx.x;
    if (i < n4) {
        const float4 v = ((const float4*)src)[i];
        ushort4 o;
        o.x = f2bf_rne(v.x); o.y = f2bf_rne(v.y);
        o.z = f2bf_rne(v.z); o.w = f2bf_rne(v.w);
        ((ushort4*)dst)[i] = o;
    }
}

// ---------------------------------------------------------------------------
// 64x64-tile fp32 GEMM (decoder only; M=16 guard): C = X@W^T + bias
// ---------------------------------------------------------------------------
#define GBM 64
#define GBN 64
#define GBK 16
#define GPAD 4

__global__ __launch_bounds__(256)
void gemm_nt_bias(const float* __restrict__ X, const float* __restrict__ W,
                  const float* __restrict__ bias, float* __restrict__ C,
                  int M, int N, int K)
{
    __shared__ float Xs[GBK][GBM + GPAD];
    __shared__ float Ws[GBK][GBN + GPAD];

    const int tid = threadIdx.x;
    const int bm = blockIdx.y * GBM;
    const int bn = blockIdx.x * GBN;
    const int tm = (tid >> 4) * 4;
    const int tn = (tid & 15) * 4;
    const int lr = tid >> 2;
    const int lc = (tid & 3) * 4;

    float acc[4][4] = {};

    for (int k0 = 0; k0 < K; k0 += GBK) {
        {
            const int gr = bm + lr;
            float4 v = make_float4(0.f, 0.f, 0.f, 0.f);
            if (gr < M) v = *(const float4*)(X + (long)gr * K + k0 + lc);
            Xs[lc + 0][lr] = v.x; Xs[lc + 1][lr] = v.y;
            Xs[lc + 2][lr] = v.z; Xs[lc + 3][lr] = v.w;
        }
        {
            const int gr = bn + lr;
            const float4 v = *(const float4*)(W + (long)gr * K + k0 + lc);
            Ws[lc + 0][lr] = v.x; Ws[lc + 1][lr] = v.y;
            Ws[lc + 2][lr] = v.z; Ws[lc + 3][lr] = v.w;
        }
        __syncthreads();
        #pragma unroll
        for (int k = 0; k < GBK; ++k) {
            const float4 a4 = *(const float4*)&Xs[k][tm];
            const float4 b4 = *(const float4*)&Ws[k][tn];
            acc[0][0] += a4.x * b4.x; acc[0][1] += a4.x * b4.y; acc[0][2] += a4.x * b4.z; acc[0][3] += a4.x * b4.w;
            acc[1][0] += a4.y * b4.x; acc[1][1] += a4.y * b4.y; acc[1][2] += a4.y * b4.z; acc[1][3] += a4.y * b4.w;
            acc[2][0] += a4.z * b4.x; acc[2][1] += a4.z * b4.y; acc[2][2] += a4.z * b4.z; acc[2][3] += a4.z * b4.w;
            acc[3][0] += a4.w * b4.x; acc[3][1] += a4.w * b4.y; acc[3][2] += a4.w * b4.z; acc[3][3] += a4.w * b4.w;
        }
        __syncthreads();
    }

    #pragma unroll
    for (int i = 0; i < 4; ++i) {
        const int gr = bm + tm + i;
        if (gr >= M) continue;
        #pragma unroll
        for (int jj = 0; jj < 4; ++jj) {
            const int gc = bn + tn + jj;
            C[(long)gr * N + gc] = acc[i][jj] + bias[gc];
        }
    }
}

// ---------------------------------------------------------------------------
// Phase-A MFMA GEMM: C[M,N] = X[M,K] @ W[N,K]^T + bias, fp32 in / fp32 out,
// bf16 internally (converted during LDS staging). Unchanged.
// ---------------------------------------------------------------------------
__global__ __launch_bounds__(256)
void gemm_mfma_a(const float* __restrict__ X,   // [M,K]
                 const float* __restrict__ W,   // [N,K]
                 const float* __restrict__ bias,// [N]
                 float* __restrict__ C,         // [M,N]
                 int M, int N, int K)
{
    __shared__ __attribute__((aligned(16))) unsigned short As[64 * 40];
    __shared__ __attribute__((aligned(16))) unsigned short Bs[128 * 40];

    const int tid  = threadIdx.x;
    const int lane = tid & 63;
    const int w    = tid >> 6;
    const int qm   = w & 1;            // 0..1 (32-row half)
    const int qn   = w >> 1;           // 0..1 (64-col half)
    const int bm   = blockIdx.y * 64;
    const int bn   = blockIdx.x * 128;
    const int al   = lane & 15;
    const int aq   = lane >> 4;

    floatx4 acc[2][4];
    #pragma unroll
    for (int i = 0; i < 2; ++i)
        #pragma unroll
        for (int j = 0; j < 4; ++j)
            acc[i][j] = (floatx4){0.f, 0.f, 0.f, 0.f};

    const int ar = tid >> 2;           // A row 0..63
    const int ak = (tid & 3) * 8;      // A k-offset {0,8,16,24}

    for (int k0 = 0; k0 < K; k0 += 32) {
        const float* ap = X + (long)(bm + ar) * K + k0 + ak;
        const float4 av0 = *(const float4*)(ap);
        const float4 av1 = *(const float4*)(ap + 4);
        float4 bv0[2], bv1[2];
        #pragma unroll
        for (int l = 0; l < 2; ++l) {
            const int c = tid + 256 * l;        // 0..511
            const float* bp = W + (long)(bn + (c >> 2)) * K + k0 + (c & 3) * 8;
            bv0[l] = *(const float4*)(bp);
            bv1[l] = *(const float4*)(bp + 4);
        }
        __syncthreads();   // previous tile's readers done
        *(uint4*)&As[ar * 40 + ak] = pack8(av0, av1);
        #pragma unroll
        for (int l = 0; l < 2; ++l) {
            const int c = tid + 256 * l;
            *(uint4*)&Bs[(c >> 2) * 40 + (c & 3) * 8] = pack8(bv0[l], bv1[l]);
        }
        __syncthreads();

        bf16x8 a[2], b[4];
        #pragma unroll
        for (int i = 0; i < 2; ++i)
            a[i] = *(const bf16x8*)&As[(qm * 32 + i * 16 + al) * 40 + aq * 8];
        #pragma unroll
        for (int j = 0; j < 4; ++j)
            b[j] = *(const bf16x8*)&Bs[(qn * 64 + j * 16 + al) * 40 + aq * 8];
        #pragma unroll
        for (int i = 0; i < 2; ++i)
            #pragma unroll
            for (int j = 0; j < 4; ++j)
                acc[i][j] = __builtin_amdgcn_mfma_f32_16x16x32_bf16(
                    a[i], b[j], acc[i][j], 0, 0, 0);
    }

    #pragma unroll
    for (int i = 0; i < 2; ++i) {
        #pragma unroll
        for (int j = 0; j < 4; ++j) {
            const int row0 = bm + qm * 32 + i * 16 + aq * 4;
            const int col  = bn + qn * 64 + j * 16 + al;
            const float bv = bias[col];
            #pragma unroll
            for (int r = 0; r < 4; ++r)
                C[(long)(row0 + r) * N + col] = acc[i][j][r] + bv;
        }
    }
}

// ---------------------------------------------------------------------------
// PERSISTENT fused pipelined GRU v4. One launch, 65 in-kernel steps.
//
// vs v3 (462 us): all cross-block state (bf16 h buffers, flags) moves to
// COHERENCE-POINT accesses (inline asm `sc0 sc1` = system scope, bypassing
// L1 + per-XCD L2). Consequences:
//  - no RELEASE fence needed: __syncthreads' vmcnt(0) guarantees the
//    sc-stores are ACKed at the coherence point before the flag store;
//  - no ACQUIRE fence needed: sc-loads can never hit a stale cached line.
// This deletes the per-step per-block L2 writeback + invalidate walks that
// v3's counters implicated (FETCH/VALU dropped across v1->v2->v3 while time
// barely moved -> sync cost, not data cost).
// Barrier: waitcnt -> sc-store own flag -> 64-lane sc-load poll (lane i
// watches block i; poll cadence = L3 latency) -> __syncthreads.
// A-fragment asm loads are fenced with s_waitcnt vmcnt(0) + sched_barrier(0)
// before the MFMAs (guide rule #18). Numerics identical to v1/v2/v3.
// ---------------------------------------------------------------------------
#define FLAG_STRIDE 4   // uints; 16 B between flags

__global__ __launch_bounds__(768, 3)
void fused_gru_persistent(const float* __restrict__ gx0,
                          const unsigned short* __restrict__ w0, const float* __restrict__ bb0,
                          const unsigned short* __restrict__ w1, const float* __restrict__ bb1,
                          const unsigned short* __restrict__ w2, const float* __restrict__ bb2,
                          unsigned short* __restrict__ h1bf0, unsigned short* __restrict__ h1bf1,
                          unsigned short* __restrict__ h2bf0, unsigned short* __restrict__ h2bf1,
                          float* __restrict__ h2last, unsigned* __restrict__ flags)
{
    __shared__ __attribute__((aligned(16))) floatx4 part[12][3][64]; // [wid][g][lane]

    const int tid   = threadIdx.x;     // 0..767
    const int lane  = tid & 63;
    const int wid   = tid >> 6;        // 0..11
    const int bx    = blockIdx.x;
    const int jbase = bx * 16;

    const int m  = wid >> 2;           // matrix: 0 w_hh0, 1 w_ih1, 2 w_hh1
    const int kh = wid & 3;            // K-quarter
    const int al = lane & 15;
    const int aq = lane >> 4;

    // ---- one-time: weight fragments -> registers ----
    const unsigned short* Wm = (m == 0) ? w0 : (m == 1) ? w1 : w2;
    const long wbase = (long)(jbase + al) * kH + kh * 256 + aq * 8;
    bf16x8 wreg[3][8];
    #pragma unroll
    for (int g = 0; g < 3; ++g)
        #pragma unroll
        for (int s = 0; s < 8; ++s)
            wreg[g][s] = *(const bf16x8*)(Wm + (long)g * kH * kH + wbase + s * 32);

    // ---- one-time: update-phase bias preload (tid<256 only) ----
    const int ub  = tid >> 4;          // batch row for update phase
    const int ujj = tid & 15;
    const int ujg = jbase + ujj;
    const float b0r = bb0[ujg], b0z = bb0[kH + ujg], b0n = bb0[2 * kH + ujg];
    const float b1r = bb1[ujg], b1z = bb1[kH + ujg], b1n = bb1[2 * kH + ujg];
    const float b2r = bb2[ujg], b2z = bb2[kH + ujg], b2n = bb2[2 * kH + ujg];

    // per-thread fp32 recursion state (update threads only)
    float h1reg = 0.f;   // h1_{k-1} for this (b,j)
    float h2reg = 0.f;   // h2_{k-2} for this (b,j)

    // A-fragment offset within an h buffer (elements)
    const int aoff = al * kH + kh * 256 + aq * 8;
    const int pl   = (ub >> 2) * 16 + ujj;   // part lane index for update read
    const int pr   = ub & 3;                 // part reg index

    // gx0 for step 0 preloaded (subsequent steps prefetched under barrier)
    float gxr = 0.f, gxz = 0.f, gxn = 0.f;
    if (tid < 256) {
        const float* g = gx0 + (long)ub * (kT * 3 * kH);
        gxr = g[ujg]; gxz = g[kH + ujg]; gxn = g[2 * kH + ujg];
    }

    for (int k = 0; k <= kT; ++k) {
        // ping-pong pointers
        const unsigned short* h1p = (k & 1) ? h1bf0 : h1bf1;   // h1_{k-1}
        unsigned short*       h1o = (k & 1) ? h1bf1 : h1bf0;   // h1_k
        const unsigned short* h2p = (k & 1) ? h2bf1 : h2bf0;   // h2_{k-2}
        unsigned short*       h2o = (k & 1) ? h2bf0 : h2bf1;   // h2_{k-1}

        // ---- A-fragments: system-scope loads from the bf16 h buffers ----
        const bool azero = (m < 2) ? (k == 0) : (k <= 1);
        const unsigned short* hsrc = (m < 2) ? h1p : h2p;
        bf16x8 a[8];
        if (!azero) {
            #pragma unroll
            for (int s = 0; s < 8; ++s)
                asm volatile("global_load_dwordx4 %0, %1, off sc0 sc1"
                             : "=&v"(a[s]) : "v"(hsrc + aoff + s * 32) : "memory");
            asm volatile("s_waitcnt vmcnt(0)" ::: "memory");
            __builtin_amdgcn_sched_barrier(0);
        } else {
            #pragma unroll
            for (int s = 0; s < 8; ++s)
                a[s] = (bf16x8){0, 0, 0, 0, 0, 0, 0, 0};
        }

        // ---- 24 MFMAs (weights + A in registers) ----
        floatx4 acc[3];
        #pragma unroll
        for (int g = 0; g < 3; ++g) acc[g] = (floatx4){0.f, 0.f, 0.f, 0.f};
        #pragma unroll
        for (int s = 0; s < 8; ++s)
            #pragma unroll
            for (int g = 0; g < 3; ++g)
                acc[g] = __builtin_amdgcn_mfma_f32_16x16x32_bf16(
                    a[s], wreg[g][s], acc[g], 0, 0, 0);

        #pragma unroll
        for (int g = 0; g < 3; ++g)
            part[wid][g][lane] = acc[g];     // ds_write_b128, conflict-free
        __syncthreads();

        // ---- cell updates (256 threads: b = tid>>4, j = tid&15) ----
        if (tid < 256) {
            float gh[3][3];
            #pragma unroll
            for (int mm = 0; mm < 3; ++mm)
                #pragma unroll
                for (int g = 0; g < 3; ++g)
                    gh[mm][g] = part[mm * 4 + 0][g][pl][pr] + part[mm * 4 + 1][g][pl][pr]
                              + part[mm * 4 + 2][g][pl][pr] + part[mm * 4 + 3][g][pl][pr];

            if (k < kT) {   // layer0 step t=k
                const float hr = gh[0][0] + b0r;
                const float hz = gh[0][1] + b0z;
                const float hn = gh[0][2] + b0n;
                const float r = 1.f / (1.f + __expf(-(gxr + hr)));
                const float z = 1.f / (1.f + __expf(-(gxz + hz)));
                const float n = tanhf(gxn + r * hn);
                const float hnew = (1.f - z) * n + z * h1reg;
                h1reg = hnew;
                store_short_sys(h1o + ub * kH + ujg, f2bf_fast_u(hnew));
            }
            if (k > 0) {    // layer1 step t=k-1; gx1 = gh[1] + b_ih1
                const float xr = gh[1][0] + b1r;
                const float xz = gh[1][1] + b1z;
                const float xn = gh[1][2] + b1n;
                const float hr = gh[2][0] + b2r;
                const float hz = gh[2][1] + b2z;
                const float hn = gh[2][2] + b2n;
                const float r = 1.f / (1.f + __expf(-(xr + hr)));
                const float z = 1.f / (1.f + __expf(-(xz + hz)));
                const float n = tanhf(xn + r * hn);
                const float hnew = (1.f - z) * n + z * h2reg;
                h2reg = hnew;
                store_short_sys(h2o + ub * kH + ujg, f2bf_fast_u(hnew));
                if (k == kT) h2last[(long)ub * kH + ujg] = hnew;  // fp32 for decoder
            }
        }

        // ---- prefetch gx0 for step k+1 (read-only; hides under barrier) ----
        float nxr = 0.f, nxz = 0.f, nxn = 0.f;
        if (tid < 256 && (k + 1) < kT) {
            const float* g = gx0 + (long)ub * (kT * 3 * kH) + (long)(k + 1) * 3 * kH;
            nxr = g[ujg]; nxz = g[kH + ujg]; nxn = g[2 * kH + ujg];
        }

        // ---- fence-free distributed-flag barrier (all state at L3) ----
        if (k < kT) {
            __syncthreads();          // per-wave vmcnt(0): sc-stores ACKed at L3
            if (wid == 0) {
                const unsigned gen = (unsigned)(k + 1);
                if (lane == 0)
                    store_dword_sys(&flags[bx * FLAG_STRIDE], gen);
                // lane i watches block i's flag; divergent loop reconverges
                // when every lane has seen its flag reach gen
                while (load_dword_sys(&flags[lane * FLAG_STRIDE]) < gen) {}
            }
            __syncthreads();
        }

        gxr = nxr; gxz = nxz; gxn = nxn;
    }
}

// ---------------------------------------------------------------------------
// kernel_launch
// ---------------------------------------------------------------------------
extern "C" void kernel_launch(void* const* d_in, const int* in_sizes, int n_in,
                              void* d_out, int out_size, void* d_ws, size_t ws_size,
                              hipStream_t stream)
{
    const float* x        = (const float*)d_in[0];   // [16,64,4096]
    const float* w_ih_l0  = (const float*)d_in[1];   // [3072,4096]
    const float* w_hh_l0  = (const float*)d_in[2];   // [3072,1024]
    const float* b_ih_l0  = (const float*)d_in[3];   // [3072]
    const float* b_hh_l0  = (const float*)d_in[4];   // [3072]
    const float* w_ih_l1  = (const float*)d_in[5];   // [3072,1024]
    const float* w_hh_l1  = (const float*)d_in[6];   // [3072,1024]
    const float* b_ih_l1  = (const float*)d_in[7];   // [3072]
    const float* b_hh_l1  = (const float*)d_in[8];   // [3072]
    const float* dec_w    = (const float*)d_in[9];   // [4096,1024]
    const float* dec_b    = (const float*)d_in[10];  // [4096]
    float* out = (float*)d_out;                      // [16,4096]

    // Workspace: gx0 12 MB + 4 bf16 h-bufs 128 KB + h2last 64 KB +
    // 3 bf16 matrices 18 MB + 1 KB flag array.
    float* ws    = (float*)d_ws;
    float* gx0   = ws;                                  // [1024,3072] rows b*T+t
    unsigned short* h1bf0 = (unsigned short*)(gx0 + (size_t)1024 * 3072);
    unsigned short* h1bf1 = h1bf0 + (size_t)kB * kH;
    unsigned short* h2bf0 = h1bf1 + (size_t)kB * kH;
    unsigned short* h2bf1 = h2bf0 + (size_t)kB * kH;
    float* h2last = (float*)(h2bf1 + (size_t)kB * kH);
    unsigned short* wbf0 = (unsigned short*)(h2last + (size_t)kB * kH);
    unsigned short* wbf1 = wbf0 + (size_t)3 * kH * kH;
    unsigned short* wbf2 = wbf1 + (size_t)3 * kH * kH;
    unsigned* flags = (unsigned*)(wbf2 + (size_t)3 * kH * kH);

    // Flags must start at 0 each replay (memset node in the graph).
    (void)hipMemsetAsync(flags, 0, 64 * FLAG_STRIDE * sizeof(unsigned), stream);

    const int wn4 = 3 * kH * kH / 4;

    // Pack recurrence weights fp32 -> bf16 (RNE)
    pack_bf16<<<(wn4 + 255) / 256, 256, 0, stream>>>(w_hh_l0, wbf0, wn4);
    pack_bf16<<<(wn4 + 255) / 256, 256, 0, stream>>>(w_ih_l1, wbf1, wn4);
    pack_bf16<<<(wn4 + 255) / 256, 256, 0, stream>>>(w_hh_l1, wbf2, wn4);

    // Phase A (MFMA bf16): gx0 = x @ w_ih_l0^T + b_ih_l0  (M=1024,N=3072,K=4096)
    gemm_mfma_a<<<dim3(3072 / 128, 1024 / 64), 256, 0, stream>>>(
        x, w_ih_l0, b_ih_l0, gx0, 1024, 3072, 4096);

    // Persistent fused recurrence: ONE launch, 65 in-kernel steps.
    fused_gru_persistent<<<64, 768, 0, stream>>>(
        gx0, wbf0, b_hh_l0, wbf1, b_ih_l1, wbf2, b_hh_l1,
        h1bf0, h1bf1, h2bf0, h2bf1, h2last, flags);

    // Decoder (fp32): out = h2_last @ dec_w^T + dec_b  (M=16,N=4096,K=1024)
    gemm_nt_bias<<<dim3(4096 / GBN, 1), 256, 0, stream>>>(
        h2last, dec_w, dec_b, out, kB, 4096, 1024);
}